// Round 7
// baseline (175.259 us; speedup 1.0000x reference)
//
#include <hip/hip_runtime.h>
#include <math.h>

// BNAF layer. B=256, W=64, I=O=64, W_IN=128. M = 16384.
// R7: TWO kernels. k_pre: swizzle w_w2 -> 32x32x16 A-frags (2 MB ws).
// k_fused: per-block (64 m) in-block hypernets + main GEMM (A=w_w2[o x k] streamed,
// B=Hw[k x m] resident 64 VGPR) + fused exp-contraction/sum-exp + final log + store.
// 512 thr = 2 i-teams x 4 (oq,mq) waves; wave-private ring, counted vmcnt(8),
// epilogue(i-1) overlapped into MFMA(i); team partials combined in LDS.
// d_out: [output (1M) | logj_out (1M)] fp32.  ws: W2F only (2,097,152 B).

typedef __attribute__((ext_vector_type(8))) short s16x8;     // 8 bf16 = 4 VGPR
typedef __attribute__((ext_vector_type(4))) float f32x4;
typedef __attribute__((ext_vector_type(16))) float f32x16;   // 32x32 MFMA C/D

#define WAITV(N) asm volatile("s_waitcnt vmcnt(" #N ")" ::: "memory")
#define WAITLGKM0 asm volatile("s_waitcnt lgkmcnt(0)" ::: "memory")
#define SB __builtin_amdgcn_sched_barrier(0)
#define ZERO16 {0.f,0.f,0.f,0.f,0.f,0.f,0.f,0.f,0.f,0.f,0.f,0.f,0.f,0.f,0.f,0.f}

__device__ inline unsigned short f2bf(float f) {
  unsigned int u = __float_as_uint(f);
  u += 0x7fffu + ((u >> 16) & 1u);
  return (unsigned short)(u >> 16);
}
__device__ inline float bf2f(unsigned short u) { return __uint_as_float(((unsigned int)u) << 16); }
__device__ inline s16x8 cvt8(float4 a, float4 b) {
  s16x8 v;
  v[0] = (short)f2bf(a.x); v[1] = (short)f2bf(a.y); v[2] = (short)f2bf(a.z); v[3] = (short)f2bf(a.w);
  v[4] = (short)f2bf(b.x); v[5] = (short)f2bf(b.y); v[6] = (short)f2bf(b.z); v[7] = (short)f2bf(b.w);
  return v;
}
__device__ inline float fast_tanh(float x) {
  float t = __expf(2.0f * x);
  return __fdividef(t - 1.0f, t + 1.0f);
}
__device__ inline void stage16(const unsigned short* gsrc, char* ldst) {
  __builtin_amdgcn_global_load_lds(
      (const __attribute__((address_space(1))) unsigned int*)gsrc,
      (__attribute__((address_space(3))) unsigned int*)ldst, 16, 0, 0);
}

// ---------------- K0: w_w2 -> 32x32x16 A-frag layout (bf16) ----------------
// Frag f = (i*2+oq)*16 + ks; lane l: o-row = oq*32+(l&31), k = ks*16+(l>>5)*8 .. +8.
__global__ __launch_bounds__(256) void k_pre(const float* __restrict__ w_w2,
                                             unsigned short* __restrict__ W2F) {
  __shared__ __align__(16) float ld[32 * 136];
  const int t = threadIdx.x, l = t & 63, w = t >> 6;
  const int b = blockIdx.x;
  const int i = b >> 2, oq = (b >> 1) & 1, kh = b & 1;
  const float* src = w_w2 + ((size_t)i * 64 + oq * 32) * 256 + kh * 128;
  #pragma unroll
  for (int v = 0; v < 4; ++v) {
    int flat = v * 1024 + t * 4;
    int row = flat >> 7, col = flat & 127;
    *(float4*)(ld + row * 136 + col) = *(const float4*)(src + (size_t)row * 256 + col);
  }
  __syncthreads();
  const int l31 = l & 31, l5 = l >> 5;
  #pragma unroll
  for (int j = 0; j < 2; ++j) {
    int ksl = w * 2 + j;
    const float* p = ld + l31 * 136 + ksl * 16 + l5 * 8;
    s16x8 fr = cvt8(*(const float4*)p, *(const float4*)(p + 4));
    *(s16x8*)(W2F + (((size_t)(i * 2 + oq) * 16) + kh * 8 + ksl) * 512 + (size_t)l * 8) = fr;
  }
}

// -------- epilogue piece: r = PART*8+G*4+j ; o = oq*32 + 16*PART + 8*G + 4*l5 + j --------
#define EPI_G(ACC, IABS, PART, G)                                                         \
  { ushort4 ev = *(const ushort4*)(ewb_l + (IABS)*64 + oq*32 + (PART)*16 + (G)*8 + l5*4); \
    float e_;                                                                             \
    e_ = __expf(ACC[(PART)*8+(G)*4+0]) * bf2f(ev.x);                                      \
    outa[(PART)*8+(G)*4+0] += xin_ * e_; sea[(PART)*8+(G)*4+0] += elj_ * e_;              \
    e_ = __expf(ACC[(PART)*8+(G)*4+1]) * bf2f(ev.y);                                      \
    outa[(PART)*8+(G)*4+1] += xin_ * e_; sea[(PART)*8+(G)*4+1] += elj_ * e_;              \
    e_ = __expf(ACC[(PART)*8+(G)*4+2]) * bf2f(ev.z);                                      \
    outa[(PART)*8+(G)*4+2] += xin_ * e_; sea[(PART)*8+(G)*4+2] += elj_ * e_;              \
    e_ = __expf(ACC[(PART)*8+(G)*4+3]) * bf2f(ev.w);                                      \
    outa[(PART)*8+(G)*4+3] += xin_ * e_; sea[(PART)*8+(G)*4+3] += elj_ * e_; }

#define EPILOG(ACC, IABS, PART)                                                           \
  { float xin_ = xin_l[(IABS)*64 + mq*32 + l31];                                          \
    float elj_ = bf2f(elj_l[(IABS)*64 + mq*32 + l31]);                                    \
    EPI_G(ACC, IABS, PART, 0) EPI_G(ACC, IABS, PART, 1) }

#define MFMA8(ACC, H)                                                                     \
  { s16x8 a0 = *(const s16x8*)(ring + ((H)*8+0)*1024 + l*16);                             \
    s16x8 a1 = *(const s16x8*)(ring + ((H)*8+1)*1024 + l*16);                             \
    s16x8 a2 = *(const s16x8*)(ring + ((H)*8+2)*1024 + l*16);                             \
    s16x8 a3 = *(const s16x8*)(ring + ((H)*8+3)*1024 + l*16);                             \
    s16x8 a4 = *(const s16x8*)(ring + ((H)*8+4)*1024 + l*16);                             \
    s16x8 a5 = *(const s16x8*)(ring + ((H)*8+5)*1024 + l*16);                             \
    s16x8 a6 = *(const s16x8*)(ring + ((H)*8+6)*1024 + l*16);                             \
    s16x8 a7 = *(const s16x8*)(ring + ((H)*8+7)*1024 + l*16);                             \
    __builtin_amdgcn_s_setprio(1);                                                        \
    ACC = __builtin_amdgcn_mfma_f32_32x32x16_bf16(a0, bh[(H)*8+0], ACC, 0, 0, 0);         \
    ACC = __builtin_amdgcn_mfma_f32_32x32x16_bf16(a1, bh[(H)*8+1], ACC, 0, 0, 0);         \
    ACC = __builtin_amdgcn_mfma_f32_32x32x16_bf16(a2, bh[(H)*8+2], ACC, 0, 0, 0);         \
    ACC = __builtin_amdgcn_mfma_f32_32x32x16_bf16(a3, bh[(H)*8+3], ACC, 0, 0, 0);         \
    ACC = __builtin_amdgcn_mfma_f32_32x32x16_bf16(a4, bh[(H)*8+4], ACC, 0, 0, 0);         \
    ACC = __builtin_amdgcn_mfma_f32_32x32x16_bf16(a5, bh[(H)*8+5], ACC, 0, 0, 0);         \
    ACC = __builtin_amdgcn_mfma_f32_32x32x16_bf16(a6, bh[(H)*8+6], ACC, 0, 0, 0);         \
    ACC = __builtin_amdgcn_mfma_f32_32x32x16_bf16(a7, bh[(H)*8+7], ACC, 0, 0, 0);         \
    __builtin_amdgcn_s_setprio(0); }

// One half-slice: counted wait, 8 ds_read + 8 MFMA, overlapped epilogue(prev), WAR wait, stage.
#define BODY_HALF(H, ACC, PRV, DOPREV, EIABS, ILAST)                                      \
  { if (!(ILAST)) { WAITV(8); } else if ((H) == 0) { WAITV(8); } else { WAITV(0); }       \
    SB;                                                                                   \
    MFMA8(ACC, H)                                                                         \
    if (DOPREV) { EPILOG(PRV, EIABS, H) }                                                 \
    WAITLGKM0; SB;                                                                        \
    if (!(ILAST)) {                                                                       \
      stage16(wp + ((H)*8+0)*512, ring + ((H)*8+0)*1024);                                 \
      stage16(wp + ((H)*8+1)*512, ring + ((H)*8+1)*1024);                                 \
      stage16(wp + ((H)*8+2)*512, ring + ((H)*8+2)*1024);                                 \
      stage16(wp + ((H)*8+3)*512, ring + ((H)*8+3)*1024);                                 \
      stage16(wp + ((H)*8+4)*512, ring + ((H)*8+4)*1024);                                 \
      stage16(wp + ((H)*8+5)*512, ring + ((H)*8+5)*1024);                                 \
      stage16(wp + ((H)*8+6)*512, ring + ((H)*8+6)*1024);                                 \
      stage16(wp + ((H)*8+7)*512, ring + ((H)*8+7)*1024);                                 \
    } }

// ---------------- K1: everything else ----------------
// LDS map: [0,131072) 8 x 16KB wave rings (pre-loop: hyper bounce + post-loop: exchange);
//          xin f32 [64i][64m] @131072 (16K); elj bf16 @147456 (8K); ewb bf16 @155648 (8K).
__global__ __launch_bounds__(512, 1) void k_fused(
    const float* __restrict__ input, const float* __restrict__ logj,
    const float* __restrict__ emb,
    const float* __restrict__ w_w1, const float* __restrict__ w_b1,
    const float* __restrict__ b_w1, const float* __restrict__ b_b1,
    const float* __restrict__ b_w2, const float* __restrict__ b_b2,
    const float* __restrict__ w_b2,
    const unsigned short* __restrict__ W2F, float* __restrict__ out) {
  __shared__ __align__(16) char smem[163840];
  float* xin_l = (float*)(smem + 131072);
  unsigned short* elj_l = (unsigned short*)(smem + 147456);
  unsigned short* ewb_l = (unsigned short*)(smem + 155648);

  const int t = threadIdx.x, l = t & 63;
  const int w = t >> 6;
  const int wu = __builtin_amdgcn_readfirstlane(w);
  const int tq = wu >> 2;                 // team = i-half
  const int wq = wu & 3, oq = wq & 1, mq = wq >> 1;
  const int lo = t & 15, hi = (t >> 4) & 3;
  const int l31 = l & 31, l5 = l >> 5;
  const int m0 = blockIdx.x * 64;

  // ---- tables ----
  {
    int mm = t & 63, ib = (t >> 6) * 8;
    const float* ip = input + (size_t)(m0 + mm) * 64 + ib;
    const float* lp = logj + (size_t)(m0 + mm) * 64 + ib;
    float4 v0 = *(const float4*)ip, v1 = *(const float4*)(ip + 4);
    float4 g0 = *(const float4*)lp, g1 = *(const float4*)(lp + 4);
    float vi[8] = {v0.x, v0.y, v0.z, v0.w, v1.x, v1.y, v1.z, v1.w};
    float gj[8] = {g0.x, g0.y, g0.z, g0.w, g1.x, g1.y, g1.z, g1.w};
    #pragma unroll
    for (int j = 0; j < 8; ++j) {
      xin_l[(ib + j) * 64 + mm] = vi[j];
      elj_l[(ib + j) * 64 + mm] = f2bf(__expf(gj[j]));
    }
    int il = t >> 3, ob = (t & 7) * 8;
    const float* wpb = w_b2 + (size_t)il * 64 + ob;
    float4 e0 = *(const float4*)wpb, e1 = *(const float4*)(wpb + 4);
    float ev[8] = {e0.x, e0.y, e0.z, e0.w, e1.x, e1.y, e1.z, e1.w};
    #pragma unroll
    for (int j = 0; j < 8; ++j) ewb_l[il * 64 + ob + j] = f2bf(__expf(ev[j]));
  }

  // ---- hypernets (16x16x32): team0 -> Hw bounce @0, team1 -> Hb bounce @32768 ----
  const float* W1 = tq ? b_w1 : w_w1;
  const float* B1b = tq ? b_b1 : w_b1;
  char* bounce = smem + tq * 32768;       // [64m][256h] bf16, XOR-swizzled
  {
    s16x8 ae[4];
    #pragma unroll
    for (int ks = 0; ks < 4; ++ks) {
      const float* p = emb + (size_t)(m0 + wq * 16 + lo) * 128 + ks * 32 + hi * 8;
      ae[ks] = cvt8(*(const float4*)p, *(const float4*)(p + 4));
    }
    #pragma unroll
    for (int nt = 0; nt < 16; ++nt) {
      f32x4 acc = {0.f, 0.f, 0.f, 0.f};
      #pragma unroll
      for (int ks = 0; ks < 4; ++ks) {
        const float* bp = W1 + (size_t)(nt * 16 + lo) * 128 + ks * 32 + hi * 8;
        s16x8 bfr = cvt8(*(const float4*)bp, *(const float4*)(bp + 4));
        acc = __builtin_amdgcn_mfma_f32_16x16x32_bf16(ae[ks], bfr, acc, 0, 0, 0);
      }
      float bv = B1b[nt * 16 + lo];
      #pragma unroll
      for (int r = 0; r < 4; ++r) {
        int row = wq * 16 + hi * 4 + r;
        int byte = row * 512 + (nt * 16 + lo) * 2;
        byte ^= ((row & 7) << 4);
        *(unsigned short*)(bounce + byte) = f2bf(fast_tanh(acc[r] + bv));
      }
    }
  }
  __syncthreads();

  // ---- bh = Hw B-frags (32x32x16: n=m=mq*32+(l&31), k=ks*16+(l>>5)*8), resident ----
  s16x8 bh[16];
  #pragma unroll
  for (int ks = 0; ks < 16; ++ks) {
    int row = mq * 32 + l31;
    int byte = row * 512 + (ks * 16 + l5 * 8) * 2;
    byte ^= ((row & 7) << 4);
    bh[ks] = *(const s16x8*)(smem + byte);
  }
  // ---- team1: b1 = Hb @ b_w2^T + b_b2 (held in regs) ----
  f32x4 b1r[4] = {{0,0,0,0},{0,0,0,0},{0,0,0,0},{0,0,0,0}};
  if (tq == 1) {
    s16x8 ab[8];
    #pragma unroll
    for (int ks = 0; ks < 8; ++ks) {
      int row = wq * 16 + lo;
      int byte = row * 512 + (ks * 32 + hi * 8) * 2;
      byte ^= ((row & 7) << 4);
      ab[ks] = *(const s16x8*)(smem + 32768 + byte);
    }
    #pragma unroll
    for (int ks = 0; ks < 8; ++ks)
      #pragma unroll
      for (int ot = 0; ot < 4; ++ot) {
        const float* bp = b_w2 + (size_t)(ot * 16 + lo) * 256 + ks * 32 + hi * 8;
        s16x8 bfr = cvt8(*(const float4*)bp, *(const float4*)(bp + 4));
        b1r[ot] = __builtin_amdgcn_mfma_f32_16x16x32_bf16(ab[ks], bfr, b1r[ot], 0, 0, 0);
      }
    #pragma unroll
    for (int ot = 0; ot < 4; ++ot) {
      float bb = b_b2[ot * 16 + lo];
      #pragma unroll
      for (int r = 0; r < 4; ++r) b1r[ot][r] += bb;
    }
  }
  __syncthreads();           // bounce reads done -> rings free; drains all mem ops
  WAITV(0); SB;              // clean vmcnt before counted pipeline

  // ---- main loop: wave-private ring, half-slice pipeline ----
  char* ring = smem + wu * 16384;
  const int ibase = tq * 32;
  const unsigned short* wp =
      W2F + ((size_t)ibase * 32 + (size_t)oq * 16) * 512 + (size_t)l * 8;
  #pragma unroll
  for (int g = 0; g < 16; ++g) stage16(wp + g * 512, ring + g * 1024);
  wp += 16384;               // -> slice ibase+1

  float outa[16], sea[16];
  #pragma unroll
  for (int z = 0; z < 16; ++z) { outa[z] = 0.f; sea[z] = 0.f; }
  f32x16 accA, accB;

  #pragma unroll 1
  for (int u = 0; u < 16; ++u) {
    const int e0 = ibase + 2 * u - 1, e1 = ibase + 2 * u;
    accA = (f32x16)ZERO16;
    BODY_HALF(0, accA, accB, (u > 0), e0, 0)
    BODY_HALF(1, accA, accB, (u > 0), e0, 0)
    wp += 16384;
    accB = (f32x16)ZERO16;
    BODY_HALF(0, accB, accA, 1, e1, (u == 15))
    BODY_HALF(1, accB, accA, 1, e1, (u == 15))
    if (u < 15) wp += 16384;
  }
  EPILOG(accB, ibase + 31, 0)
  EPILOG(accB, ibase + 31, 1)

  // ---- team combine in LDS (pitch 66 avoids conflicts), coalesced final store ----
  __syncthreads();
  {
    float* oaT = (float*)smem + (size_t)tq * 4224;
    float* seT = (float*)smem + 8448 + (size_t)tq * 4224;
    float* b1L = (float*)smem + 16896;
    #pragma unroll
    for (int r = 0; r < 16; ++r) {
      int o = oq * 32 + (r & 3) + 8 * (r >> 2) + 4 * l5;
      int m = mq * 32 + l31;
      oaT[m * 66 + o] = outa[r];
      seT[m * 66 + o] = sea[r];
    }
    if (tq == 1) {
      #pragma unroll
      for (int ot = 0; ot < 4; ++ot)
        #pragma unroll
        for (int r2 = 0; r2 < 4; ++r2)
          b1L[(wq * 16 + hi * 4 + r2) * 66 + ot * 16 + lo] = b1r[ot][r2];
    }
  }
  __syncthreads();
  {
    const float* base = (const float*)smem;
    int flat = t * 8;
    int m = flat >> 6, o = flat & 63;
    float vo[8], vl[8];
    #pragma unroll
    for (int j = 0; j < 8; ++j) {
      int idx = m * 66 + o + j;
      vo[j] = base[idx] + base[4224 + idx] + base[16896 + idx];
      vl[j] = __logf(base[8448 + idx] + base[8448 + 4224 + idx]);
    }
    size_t ob = (size_t)(m0 + m) * 64 + o;
    float4 s0 = {vo[0], vo[1], vo[2], vo[3]}, s1 = {vo[4], vo[5], vo[6], vo[7]};
    float4 t0 = {vl[0], vl[1], vl[2], vl[3]}, t1 = {vl[4], vl[5], vl[6], vl[7]};
    *(float4*)(out + ob) = s0;
    *(float4*)(out + ob + 4) = s1;
    *(float4*)(out + 1048576 + ob) = t0;
    *(float4*)(out + 1048576 + ob + 4) = t1;
  }
}

extern "C" void kernel_launch(void* const* d_in, const int* in_sizes, int n_in,
                              void* d_out, int out_size, void* d_ws, size_t ws_size,
                              hipStream_t stream) {
  const float* input = (const float*)d_in[0];
  const float* w_emb = (const float*)d_in[1];
  const float* logj  = (const float*)d_in[2];
  const float* w_w1  = (const float*)d_in[3];
  const float* w_b1  = (const float*)d_in[4];
  const float* w_w2  = (const float*)d_in[5];
  const float* w_b2  = (const float*)d_in[6];
  const float* b_w1  = (const float*)d_in[7];
  const float* b_b1  = (const float*)d_in[8];
  const float* b_w2  = (const float*)d_in[9];
  const float* b_b2  = (const float*)d_in[10];
  float* out = (float*)d_out;

  unsigned short* W2F = (unsigned short*)d_ws;   // 2,097,152 B

  hipLaunchKernelGGL(k_pre, dim3(256), dim3(256), 0, stream, w_w2, W2F);
  hipLaunchKernelGGL(k_fused, dim3(256), dim3(512), 0, stream,
                     input, logj, w_emb, w_w1, w_b1, b_w1, b_b1, b_w2, b_b2, w_b2,
                     W2F, out);
}